// Round 2
// baseline (19805.095 us; speedup 1.0000x reference)
//
#include <hip/hip_runtime.h>
#include <math.h>

#define TWO_PI_F 6.2831853071795864769f

constexpr int T     = 256;
constexpr int BATCH = 32;
constexpr int NIN   = 28;
constexpr int NH    = 1024;
constexpr int NOUT  = 10;

constexpr int NGROUP = 4;              // groups; each owns 8 batches
constexpr int BPG    = 64;             // blocks per group (16 Wh rows each)
constexpr int NBLK   = NGROUP * BPG;   // 256 blocks = 1/CU  (coop-launch safe)
constexpr int NTHR   = 512;            // 8 waves: 4 row-groups x 2 batch-groups
constexpr int ROWS   = NH / BPG;       // 16 rows of Wh per block
constexpr int BPB    = BATCH / NGROUP; // 8 batches per group

// ws layout (float offsets)
constexpr int WS_SC  = 0;                 // sin state [2][32][1024]
constexpr int WS_CC  = 2 * BATCH * NH;    // cos state [2][32][1024]
constexpr int WS_STF = 4 * BATCH * NH;    // final theta [32][1024]
constexpr int WS_CTR = 5 * BATCH * NH;    // barrier counters, 64 uints (256B) per group

__device__ __forceinline__ float2 lo2(float4 v) { return make_float2(v.x, v.y); }
__device__ __forceinline__ float2 hi2(float4 v) { return make_float2(v.z, v.w); }

__device__ __forceinline__ void gbar(unsigned* ctr, unsigned target) {
  __threadfence();        // release my sc/cc stores to device scope
  __syncthreads();        // all waves of this block have fenced
  if (threadIdx.x == 0) {
    atomicAdd(ctr, 1u);   // device-scope by default
    while (__hip_atomic_load(ctr, __ATOMIC_RELAXED, __HIP_MEMORY_SCOPE_AGENT) < target) {
      __builtin_amdgcn_s_sleep(2);
    }
  }
  __syncthreads();
  __threadfence();        // acquire: invalidate stale cache lines before reading peers
}

__global__ __launch_bounds__(NTHR, 2) void kuramoto_scan(
    const float* __restrict__ x,      // [T][32][28]
    const float* __restrict__ Wi_w,   // [1024][28]
    const float* __restrict__ Wi_b,   // [1024]
    const float* __restrict__ Wh,     // [1024][1024]
    const float* __restrict__ omega,  // [1024]
    float* __restrict__ ws)
{
  __shared__ float wt[ROWS * NH];     // 64 KB: my 16 rows of Wh, resident all 256 steps

  const int tid = threadIdx.x;
  const int bid = blockIdx.x;
  const int grp = bid & (NGROUP - 1);
  const int blk = bid >> 2;           // 0..63 -> 16-row slice
  const int h0  = blk * ROWS;
  const int b0  = grp * BPB;

  float* sc  = ws + WS_SC;
  float* cc  = ws + WS_CC;
  float* stF = ws + WS_STF;
  unsigned* ctr = (unsigned*)(ws + WS_CTR) + grp * 64; // 256B apart per group

  // ---- stage Wh tile into LDS (once) ----
  for (int idx = tid; idx < ROWS * (NH / 4); idx += NTHR) {
    const int i = idx >> 8;          // row 0..15
    const int q = idx & 255;         // quad 0..255
    *(float4*)&wt[i * NH + q * 4] = *(const float4*)&Wh[(size_t)(h0 + i) * NH + q * 4];
  }

  const int lane = tid & 63;
  const int ig   = tid >> 6;         // wave 0..7
  const int rg   = ig >> 1;          // row group 0..3  -> rows h0+rg*4 .. +3
  const int bg   = ig & 1;           // batch group 0..1 -> batches b0+bg*4 .. +3
  const int bB   = b0 + bg * 4;      // first batch this wave handles

  // ---- writer-lane state (lane < 16 owns (r = lane>>2, b = lane&3)) ----
  float th_own = 0.f, s_own = 0.f, c_own = 1.f;
  float wi[NIN];
  float bias = 0.f;
  int my_b = 0, my_i = 0;
  if (lane < 16) {
    my_i = h0 + rg * 4 + (lane >> 2);
    my_b = bB + (lane & 3);
    bias = Wi_b[my_i] + omega[my_i];
#pragma unroll
    for (int k = 0; k < NIN; ++k) wi[k] = Wi_w[my_i * NIN + k];
    // state0 = 0 -> sin=0, cos=1 into parity-0 buffers
    sc[0 * BATCH * NH + my_b * NH + my_i] = 0.f;
    cc[0 * BATCH * NH + my_b * NH + my_i] = 1.f;
  }

  unsigned phase = 1;
  gbar(ctr, BPG * phase); ++phase;   // init barrier: tiles + state-0 visible

  const int jb = lane * 4;

  for (int t = 0; t < T; ++t) {
    const int p = t & 1;
    const float* scp = sc + p * BATCH * NH + bB * NH;
    const float* ccp = cc + p * BATCH * NH + bB * NH;

    float2 accS[4][4], accC[4][4];   // [row r][batch b], packed pairs
#pragma unroll
    for (int r = 0; r < 4; ++r)
#pragma unroll
      for (int b = 0; b < 4; ++b) {
        accS[r][b] = make_float2(0.f, 0.f);
        accC[r][b] = make_float2(0.f, 0.f);
      }

#pragma unroll
    for (int u = 0; u < 4; ++u) {
      const int j = jb + u * 256;    // this lane's j-quad
      float4 w4[4];
#pragma unroll
      for (int r = 0; r < 4; ++r)
        w4[r] = *(const float4*)&wt[(rg * 4 + r) * NH + j];
#pragma unroll
      for (int b = 0; b < 4; ++b) {
        const float4 s4 = *(const float4*)&scp[b * NH + j];
        const float4 c4 = *(const float4*)&ccp[b * NH + j];
        const float2 sl = lo2(s4), sh = hi2(s4);
        const float2 cl = lo2(c4), ch = hi2(c4);
#pragma unroll
        for (int r = 0; r < 4; ++r) {
          const float2 wl = lo2(w4[r]), wh = hi2(w4[r]);
          accS[r][b] += wl * sl + wh * sh;
          accC[r][b] += wl * cl + wh * ch;
        }
      }
    }

    // collapse pairs, then full-wave butterfly: every lane ends with all totals
    float aSv[16], aCv[16];
#pragma unroll
    for (int r = 0; r < 4; ++r)
#pragma unroll
      for (int b = 0; b < 4; ++b) {
        float vs = accS[r][b].x + accS[r][b].y;
        float vc = accC[r][b].x + accC[r][b].y;
#pragma unroll
        for (int st = 1; st < 64; st <<= 1) {
          vs += __shfl_xor(vs, st, 64);
          vc += __shfl_xor(vc, st, 64);
        }
        aSv[r * 4 + b] = vs;
        aCv[r * 4 + b] = vc;
      }

    // select my (r,b) sums without runtime register indexing
    float aS = aSv[0], aC = aCv[0];
#pragma unroll
    for (int k = 1; k < 16; ++k) {
      const bool m = (lane == k);
      aS = m ? aSv[k] : aS;
      aC = m ? aCv[k] : aC;
    }

    if (lane < 16) {
      // coupling_i = sin(th_i)*Σ Wh·cos  -  cos(th_i)*Σ Wh·sin
      const float coup = s_own * aC - c_own * aS;
      const float* xr = x + (size_t)(t * BATCH + my_b) * NIN;
      float inp = bias;
#pragma unroll
      for (int k = 0; k < NIN; ++k) inp += xr[k] * wi[k];

      float th = coup + inp + th_own;
      th = fmodf(th, TWO_PI_F);
      if (th < 0.f) th += TWO_PI_F;
      th_own = th;
      sincosf(th, &s_own, &c_own);

      const int pn = p ^ 1;
      sc[pn * BATCH * NH + my_b * NH + my_i] = s_own;
      cc[pn * BATCH * NH + my_b * NH + my_i] = c_own;
      if (t == T - 1) stF[my_b * NH + my_i] = th;
    }

    gbar(ctr, BPG * phase); ++phase;
  }
}

__global__ void readout(const float* __restrict__ ws,
                        const float* __restrict__ Wout,   // [10][1024]
                        const float* __restrict__ bout,   // [10]
                        float* __restrict__ out)          // [32][10]
{
  const float* stF = ws + WS_STF;
  const int b = blockIdx.x;
  const int lane = threadIdx.x;   // 64 threads
  float st[16];
#pragma unroll
  for (int u = 0; u < 16; ++u) st[u] = stF[b * NH + u * 64 + lane];
  for (int o = 0; o < NOUT; ++o) {
    float acc = 0.f;
#pragma unroll
    for (int u = 0; u < 16; ++u) acc += st[u] * Wout[o * NH + u * 64 + lane];
#pragma unroll
    for (int st2 = 1; st2 < 64; st2 <<= 1) acc += __shfl_xor(acc, st2, 64);
    if (lane == 0) out[b * NOUT + o] = acc + bout[o];
  }
}

extern "C" void kernel_launch(void* const* d_in, const int* in_sizes, int n_in,
                              void* d_out, int out_size, void* d_ws, size_t ws_size,
                              hipStream_t stream) {
  const float* x     = (const float*)d_in[0];
  const float* Wi_w  = (const float*)d_in[1];
  const float* Wi_b  = (const float*)d_in[2];
  const float* Wh    = (const float*)d_in[3];
  const float* omega = (const float*)d_in[4];
  const float* W_out = (const float*)d_in[5];
  const float* b_out = (const float*)d_in[6];
  float* ws = (float*)d_ws;

  // zero the barrier counters (ws is poisoned 0xAA before every timed launch)
  hipMemsetAsync((char*)d_ws + (size_t)WS_CTR * 4, 0, 4096, stream);

  void* args[] = { (void*)&x, (void*)&Wi_w, (void*)&Wi_b, (void*)&Wh,
                   (void*)&omega, (void*)&ws };
  hipError_t err = hipLaunchCooperativeKernel((const void*)kuramoto_scan,
                                              dim3(NBLK), dim3(NTHR), args, 0, stream);
  if (err != hipSuccess) {
    // validation rejected the cooperative launch; fall back to a normal launch.
    // 256 blocks at 1 block/CU (guaranteed by __launch_bounds__) are fully
    // co-resident on the idle device, so the hand-rolled barrier is safe.
    (void)hipGetLastError();
    kuramoto_scan<<<dim3(NBLK), dim3(NTHR), 0, stream>>>(x, Wi_w, Wi_b, Wh, omega, ws);
  }

  readout<<<dim3(BATCH), dim3(64), 0, stream>>>(ws, W_out, b_out, (float*)d_out);
}

// Round 3
// 7753.470 us; speedup vs baseline: 2.5544x; 2.5544x over previous
//
#include <hip/hip_runtime.h>
#include <math.h>

#define TWO_PI_F 6.2831853071795864769f

constexpr int T     = 256;
constexpr int BATCH = 32;
constexpr int NIN   = 28;
constexpr int NH    = 1024;
constexpr int NOUT  = 10;

constexpr int SCAN_THR = 1024;   // 16 waves
constexpr int JG  = 4;           // j-groups per block
constexpr int TPG = 256;         // threads per j-group
constexpr int RPT = 4;           // rows per thread in the j-loop
constexpr int JPG = NH / JG;     // 256 j-columns per group

// ws layout (float offsets)
constexpr size_t WS_WHT = 0;                   // WhT [1024][1024] (transposed Wh)
constexpr size_t WS_STF = (size_t)NH * NH;     // final theta [32][1024]

// ---------------- transpose Wh -> WhT (once per launch) ----------------
__global__ __launch_bounds__(256) void transpose_wh(const float* __restrict__ Wh,
                                                    float* __restrict__ wht)
{
  __shared__ float tile[64][65];
  const int i0 = blockIdx.y * 64, j0 = blockIdx.x * 64;
  const int t  = threadIdx.x;
  const int li = t >> 4;          // 0..15
  const int lj = (t & 15) * 4;    // 0,4,..,60
#pragma unroll
  for (int k = 0; k < 4; ++k) {
    const int i = li + 16 * k;
    const float4 v = *(const float4*)&Wh[(size_t)(i0 + i) * NH + j0 + lj];
    tile[i][lj + 0] = v.x; tile[i][lj + 1] = v.y;
    tile[i][lj + 2] = v.z; tile[i][lj + 3] = v.w;
  }
  __syncthreads();
#pragma unroll
  for (int k = 0; k < 4; ++k) {
    const int j = li + 16 * k;
    const float4 v = make_float4(tile[lj + 0][j], tile[lj + 1][j],
                                 tile[lj + 2][j], tile[lj + 3][j]);
    *(float4*)&wht[(size_t)(j0 + j) * NH + i0 + lj] = v;   // wht[j][i] = Wh[i][j]
  }
}

// ---------------- the scan: one block per batch, zero cross-block sync ----------------
__global__ __launch_bounds__(SCAN_THR) void kuramoto_scan(
    const float* __restrict__ x,      // [T][32][28]
    const float* __restrict__ Wi_w,   // [1024][28]
    const float* __restrict__ Wi_b,   // [1024]
    const float* __restrict__ omega,  // [1024]
    const float* __restrict__ wht,    // [1024][1024] transposed
    float* __restrict__ stF)          // [32][1024]
{
  __shared__ __align__(16) float2 sc[NH];        // (sin, cos) per hidden unit: 8 KB
  __shared__ __align__(16) float2 part[NH][JG];  // per-group partial (S, C): 32 KB

  const int b   = blockIdx.x;
  const int tid = threadIdx.x;
  const int jg  = tid >> 8;        // j-group 0..3
  const int tt  = tid & (TPG - 1); // thread-in-group 0..255
  const int r0  = tt * RPT;        // j-loop rows r0..r0+3
  const int jbase = jg * JPG;
  const int my_i  = tid;           // state-update row owned by this thread

  float th = 0.f;                                   // theta, persistent in regs
  const float bw = Wi_b[my_i] + omega[my_i];

  sc[my_i] = make_float2(0.f, 1.f);                 // theta0 = 0
  __syncthreads();

  const float4* wbase = (const float4*)wht + (size_t)jbase * (NH / 4) + tt;

  for (int t = 0; t < T; ++t) {
    // ---- j-slice matvec: acc (S,C) for rows r0..r0+3 over j in [jbase, jbase+JPG) ----
    float2 a0 = make_float2(0.f, 0.f), a1 = a0, a2 = a0, a3 = a0;
    const float4* wp = wbase;
#pragma unroll 8
    for (int jj = 0; jj < JPG; ++jj) {
      const float2 scj = sc[jbase + jj];            // LDS broadcast (wave-uniform addr)
      const float4 w   = wp[(size_t)jj * (NH / 4)]; // WhT[j][r0..r0+3], coalesced
      a0 += make_float2(w.x, w.x) * scj;            // v_pk_fma_f32: (S,C) pair per row
      a1 += make_float2(w.y, w.y) * scj;
      a2 += make_float2(w.z, w.z) * scj;
      a3 += make_float2(w.w, w.w) * scj;
    }
    part[r0 + 0][jg] = a0;
    part[r0 + 1][jg] = a1;
    part[r0 + 2][jg] = a2;
    part[r0 + 3][jg] = a3;
    __syncthreads();   // all sc reads + partial writes done

    // ---- finalize row my_i: combine 4 partials, theta update ----
    const float4 p01 = *(const float4*)&part[my_i][0];  // (S0,C0,S1,C1)
    const float4 p23 = *(const float4*)&part[my_i][2];  // (S2,C2,S3,C3)
    const float S = p01.x + p01.z + p23.x + p23.z;
    const float C = p01.y + p01.w + p23.y + p23.w;
    const float2 scm = sc[my_i];                        // sin/cos of current theta
    const float coup = scm.x * C - scm.y * S;           // sin*ΣWcos - cos*ΣWsin

    const float* xr  = x + ((size_t)t * BATCH + b) * NIN;
    const float* wir = Wi_w + (size_t)my_i * NIN;
    float inp = bw;
#pragma unroll
    for (int k = 0; k < NIN; ++k) inp += xr[k] * wir[k];

    th = coup + inp + th;
    th = fmodf(th, TWO_PI_F);
    if (th < 0.f) th += TWO_PI_F;
    float s, c;
    sincosf(th, &s, &c);
    sc[my_i] = make_float2(s, c);   // own-row write; no race with own read above
    __syncthreads();                // new state visible before next j-loop
  }

  stF[(size_t)b * NH + my_i] = th;
}

// ---------------- readout ----------------
__global__ void readout(const float* __restrict__ stF,
                        const float* __restrict__ Wout,   // [10][1024]
                        const float* __restrict__ bout,   // [10]
                        float* __restrict__ out)          // [32][10]
{
  const int b = blockIdx.x;
  const int lane = threadIdx.x;   // 64 threads
  float st[16];
#pragma unroll
  for (int u = 0; u < 16; ++u) st[u] = stF[(size_t)b * NH + u * 64 + lane];
  for (int o = 0; o < NOUT; ++o) {
    float acc = 0.f;
#pragma unroll
    for (int u = 0; u < 16; ++u) acc += st[u] * Wout[o * NH + u * 64 + lane];
#pragma unroll
    for (int st2 = 1; st2 < 64; st2 <<= 1) acc += __shfl_xor(acc, st2, 64);
    if (lane == 0) out[b * NOUT + o] = acc + bout[o];
  }
}

extern "C" void kernel_launch(void* const* d_in, const int* in_sizes, int n_in,
                              void* d_out, int out_size, void* d_ws, size_t ws_size,
                              hipStream_t stream) {
  const float* x     = (const float*)d_in[0];
  const float* Wi_w  = (const float*)d_in[1];
  const float* Wi_b  = (const float*)d_in[2];
  const float* Wh    = (const float*)d_in[3];
  const float* omega = (const float*)d_in[4];
  const float* W_out = (const float*)d_in[5];
  const float* b_out = (const float*)d_in[6];
  float* ws = (float*)d_ws;

  float* wht = ws + WS_WHT;
  float* stF = ws + WS_STF;

  transpose_wh<<<dim3(NH / 64, NH / 64), dim3(256), 0, stream>>>(Wh, wht);
  kuramoto_scan<<<dim3(BATCH), dim3(SCAN_THR), 0, stream>>>(
      x, Wi_w, Wi_b, omega, wht, stF);
  readout<<<dim3(BATCH), dim3(64), 0, stream>>>(stF, W_out, b_out, (float*)d_out);
}

// Round 4
// 3595.938 us; speedup vs baseline: 5.5076x; 2.1562x over previous
//
#include <hip/hip_runtime.h>
#include <hip/hip_fp16.h>
#include <math.h>

#define TWO_PI_F 6.2831853071795864769f

constexpr int T     = 256;
constexpr int BATCH = 32;
constexpr int NIN   = 28;
constexpr int NH    = 1024;
constexpr int NOUT  = 10;

constexpr int NBLK   = 64;            // blocks; block k owns rows [16k,16k+16)
constexpr int NTHR   = 512;           // 8 waves: thread = (il = tid>>5, b = tid&31)
constexpr int ROWS   = NH / NBLK;     // 16
constexpr int JP     = NH / 2;        // 512 j-pairs
constexpr int CHUNK  = 32;            // j-pairs per staged chunk
constexpr int NCHUNK = JP / CHUNK;    // 16

typedef unsigned int uint;
typedef unsigned long long ull;
typedef _Float16 h2 __attribute__((ext_vector_type(2)));

// ---- ws byte offsets ----
constexpr size_t OFF_WPK = 0;                                   // uint [NH][JP]  = 2 MB (fp16 W j-pairs)
constexpr size_t OFF_INP = 2ull * 1024 * 1024;                  // float [T][NH][BATCH] = 32 MB
constexpr size_t OFF_SCG = OFF_INP + (size_t)T * NH * BATCH * 4;// ull [2][JP][BATCH] = 256 KB (s-pair|c-pair)
constexpr size_t OFF_STF = OFF_SCG + 2ull * JP * BATCH * 8;     // float [BATCH][NH] = 128 KB
constexpr size_t OFF_CTR = OFF_STF + (size_t)BATCH * NH * 4;    // barrier flags, 8 KB

__device__ __forceinline__ float fdot2p(uint a, uint b, float c) {
#if __has_builtin(__builtin_amdgcn_fdot2)
  return __builtin_amdgcn_fdot2(__builtin_bit_cast(h2, a), __builtin_bit_cast(h2, b), c, false);
#else
  __half2 ha = __builtin_bit_cast(__half2, a), hb = __builtin_bit_cast(__half2, b);
  return c + __low2float(ha) * __low2float(hb) + __high2float(ha) * __high2float(hb);
#endif
}

__device__ __forceinline__ uint2 ld_sc(const ull* p) {
  ull v = __hip_atomic_load(p, __ATOMIC_RELAXED, __HIP_MEMORY_SCOPE_AGENT);
  uint2 r; r.x = (uint)v; r.y = (uint)(v >> 32); return r;
}
__device__ __forceinline__ void st_sc(ull* p, uint lo, uint hi) {
  __hip_atomic_store(p, (ull)lo | ((ull)hi << 32), __ATOMIC_RELAXED, __HIP_MEMORY_SCOPE_AGENT);
}

// Parallel-flag grid barrier: one sc1 store + 64 independent polls. No atomic
// serialization, no threadfence (state traffic is sc1/L2-bypassing, and
// __syncthreads' vmcnt(0) drain makes each wave's stores LLC-visible).
__device__ __forceinline__ void gbar(unsigned* flags, unsigned step, int tid, int bid) {
  __syncthreads();
  if (tid == 0)
    __hip_atomic_store(&flags[bid * 32], step, __ATOMIC_RELEASE, __HIP_MEMORY_SCOPE_AGENT);
  if (tid < NBLK)
    while (__hip_atomic_load(&flags[tid * 32], __ATOMIC_RELAXED, __HIP_MEMORY_SCOPE_AGENT) < step)
      __builtin_amdgcn_s_sleep(1);
  __syncthreads();
}

// ---- prep: W[i][2jp..2jp+1] -> packed fp16 pair ----
__global__ __launch_bounds__(256) void prep_w(const float* __restrict__ Wh,
                                              uint* __restrict__ wpk) {
  const int m = blockIdx.x * 256 + threadIdx.x;   // m = i*512 + jp
  const int i = m >> 9, jp = m & 511;
  const float2 v = *(const float2*)&Wh[(size_t)i * NH + 2 * jp];
  wpk[m] = __builtin_bit_cast(uint, __floats2half2_rn(v.x, v.y)); // lo = W[i][2jp]
}

// ---- prep: inp[t][i][b] = Wi_w[i,:]·x[t,b,:] + Wi_b[i] + omega[i] ----
__global__ __launch_bounds__(256) void prep_inp(const float* __restrict__ x,
                                                const float* __restrict__ Wi_w,
                                                const float* __restrict__ Wi_b,
                                                const float* __restrict__ omega,
                                                float* __restrict__ inp) {
  const int t  = blockIdx.x;
  const int il = threadIdx.x >> 5, b = threadIdx.x & 31;
  const int i  = blockIdx.y * 8 + il;
  const float* xr = x + ((size_t)t * BATCH + b) * NIN;
  const float* wr = Wi_w + (size_t)i * NIN;
  float acc = Wi_b[i] + omega[i];
#pragma unroll
  for (int k = 0; k < NIN; ++k) acc += xr[k] * wr[k];
  inp[((size_t)t * NH + i) * BATCH + b] = acc;
}

// ---- the scan: W partitioned in LDS, state exchanged via sc1 atomics ----
__global__ __launch_bounds__(NTHR) void kuramoto_scan(
    const float* __restrict__ inp,    // [T][NH][BATCH]
    const uint*  __restrict__ wpk,    // [NH][JP] fp16 pairs
    ull*         __restrict__ scg,    // [2][JP][BATCH] (s-pair, c-pair)
    float*       __restrict__ stF,    // [BATCH][NH]
    unsigned*    __restrict__ flags)
{
  __shared__ uint  wlds[ROWS * JP];          // 32 KB: my 16 rows, fp16 j-pairs
  __shared__ uint2 stage[2][CHUNK * BATCH];  // 16 KB: double-buffered state chunks
  __shared__ uint  newsc[ROWS * BATCH];      // 2 KB: half2(s,c) for pair-packing

  const int tid = threadIdx.x;
  const int bid = blockIdx.x;
  const int il  = tid >> 5;                  // 0..15
  const int b   = tid & 31;
  const int i   = bid * ROWS + il;           // my hidden unit

  // W slice -> LDS (linear copy; wpk rows [16k,16k+16) are contiguous)
  for (int m = tid; m < ROWS * JP; m += NTHR)
    wlds[m] = wpk[(size_t)bid * ROWS * JP + m];

  // init state pairs for my rows (theta0 = 0 -> s=0, c=1): jp in [8*bid, 8*bid+8)
  if (tid < 8 * BATCH) {
    const int jl = tid >> 5, bb = tid & 31;
    st_sc(scg + (size_t)(bid * 8 + jl) * BATCH + bb, 0x00000000u, 0x3C003C00u);
  }

  float th = 0.f, s_own = 0.f, c_own = 1.f;
  unsigned step = 1;
  gbar(flags, step, tid, bid); ++step;

  const uint* wrow = wlds + il * JP;

  for (int t = 0; t < T; ++t) {
    const int p = t & 1;
    const ull* src = scg + (size_t)p * JP * BATCH;

    float accS = 0.f, accC = 0.f;
    uint2 r0 = ld_sc(src + tid), r1 = ld_sc(src + 512 + tid);

    for (int c = 0; c < NCHUNK; ++c) {
      const int buf = c & 1;
      stage[buf][tid]       = r0;
      stage[buf][tid + 512] = r1;
      if (c + 1 < NCHUNK) {
        r0 = ld_sc(src + (c + 1) * 1024 + tid);
        r1 = ld_sc(src + (c + 1) * 1024 + 512 + tid);
      }
      __syncthreads();   // chunk staged; also guards buf reuse (see note)
      const uint2* st = &stage[buf][b];       // index stride 32 per jp
      const uint*  wr = wrow + c * CHUNK;
#pragma unroll
      for (int q = 0; q < CHUNK / 4; ++q) {
        const uint4 w4 = *(const uint4*)&wr[q * 4];
        const uint2 e0 = st[(q * 4 + 0) * 32];
        const uint2 e1 = st[(q * 4 + 1) * 32];
        const uint2 e2 = st[(q * 4 + 2) * 32];
        const uint2 e3 = st[(q * 4 + 3) * 32];
        accS = fdot2p(w4.x, e0.x, accS); accC = fdot2p(w4.x, e0.y, accC);
        accS = fdot2p(w4.y, e1.x, accS); accC = fdot2p(w4.y, e1.y, accC);
        accS = fdot2p(w4.z, e2.x, accS); accC = fdot2p(w4.z, e2.y, accC);
        accS = fdot2p(w4.w, e3.x, accS); accC = fdot2p(w4.w, e3.y, accC);
      }
    }

    // ---- theta update for (i, b) ----
    const float coup = s_own * accC - c_own * accS;
    const float inpv = inp[((size_t)t * NH + i) * BATCH + b];
    th = fmodf(coup + inpv + th, TWO_PI_F);
    if (th < 0.f) th += TWO_PI_F;
    __builtin_amdgcn_s_setprio(1);
    float s, c;
    sincosf(th, &s, &c);
    __builtin_amdgcn_s_setprio(0);
    s_own = s; c_own = c;

    if (t == T - 1) break;

    // pack (s,c) -> fp16 pairs -> publish to next-parity buffer
    newsc[il * 32 + b] = __builtin_bit_cast(uint, __floats2half2_rn(s, c)); // lo=s, hi=c
    __syncthreads();
    if (tid < 8 * BATCH) {
      const int jl = tid >> 5, bb = tid & 31;
      const uint a0 = newsc[(2 * jl) * 32 + bb];
      const uint a1 = newsc[(2 * jl + 1) * 32 + bb];
      const uint spair = (a0 & 0xFFFFu) | (a1 << 16);
      const uint cpair = (a0 >> 16) | (a1 & 0xFFFF0000u);
      st_sc(scg + (size_t)(p ^ 1) * JP * BATCH + (size_t)(bid * 8 + jl) * BATCH + bb,
            spair, cpair);
    }
    gbar(flags, step, tid, bid); ++step;
  }

  stF[(size_t)b * NH + i] = th;
}

// ---- readout ----
__global__ void readout(const float* __restrict__ stF,
                        const float* __restrict__ Wout,   // [10][1024]
                        const float* __restrict__ bout,   // [10]
                        float* __restrict__ out)          // [32][10]
{
  const int bb = blockIdx.x;
  const int lane = threadIdx.x;   // 64 threads
  float st[16];
#pragma unroll
  for (int u = 0; u < 16; ++u) st[u] = stF[(size_t)bb * NH + u * 64 + lane];
  for (int o = 0; o < NOUT; ++o) {
    float acc = 0.f;
#pragma unroll
    for (int u = 0; u < 16; ++u) acc += st[u] * Wout[o * NH + u * 64 + lane];
#pragma unroll
    for (int sh = 1; sh < 64; sh <<= 1) acc += __shfl_xor(acc, sh, 64);
    if (lane == 0) out[bb * NOUT + o] = acc + bout[o];
  }
}

extern "C" void kernel_launch(void* const* d_in, const int* in_sizes, int n_in,
                              void* d_out, int out_size, void* d_ws, size_t ws_size,
                              hipStream_t stream) {
  const float* x     = (const float*)d_in[0];
  const float* Wi_w  = (const float*)d_in[1];
  const float* Wi_b  = (const float*)d_in[2];
  const float* Wh    = (const float*)d_in[3];
  const float* omega = (const float*)d_in[4];
  const float* W_out = (const float*)d_in[5];
  const float* b_out = (const float*)d_in[6];

  char* ws = (char*)d_ws;
  uint*     wpk  = (uint*)(ws + OFF_WPK);
  float*    inp  = (float*)(ws + OFF_INP);
  ull*      scg  = (ull*)(ws + OFF_SCG);
  float*    stF  = (float*)(ws + OFF_STF);
  unsigned* flg  = (unsigned*)(ws + OFF_CTR);

  hipMemsetAsync(ws + OFF_CTR, 0, 8192, stream);

  prep_w<<<dim3(NH * JP / 256), dim3(256), 0, stream>>>(Wh, wpk);
  prep_inp<<<dim3(T, NH / 8), dim3(256), 0, stream>>>(x, Wi_w, Wi_b, omega, inp);

  void* args[] = { (void*)&inp, (void*)&wpk, (void*)&scg, (void*)&stF, (void*)&flg };
  hipError_t err = hipLaunchCooperativeKernel((const void*)kuramoto_scan,
                                              dim3(NBLK), dim3(NTHR), args, 0, stream);
  if (err != hipSuccess) {
    // 64 blocks at 1/CU are trivially co-resident; normal launch is safe.
    (void)hipGetLastError();
    kuramoto_scan<<<dim3(NBLK), dim3(NTHR), 0, stream>>>(inp, wpk, scg, stF, flg);
  }

  readout<<<dim3(BATCH), dim3(64), 0, stream>>>(stF, W_out, b_out, (float*)d_out);
}

// Round 5
// 2588.137 us; speedup vs baseline: 7.6523x; 1.3894x over previous
//
#include <hip/hip_runtime.h>
#include <hip/hip_fp16.h>
#include <math.h>

#define TWO_PI_F 6.2831853071795864769f

constexpr int T     = 256;
constexpr int BATCH = 32;
constexpr int NIN   = 28;
constexpr int NH    = 1024;
constexpr int NOUT  = 10;

constexpr int NBLK = 64;          // block k owns hidden rows [16k, 16k+16)
constexpr int NTHR = 512;         // 8 waves: wave w -> (ntile = w&3, khalf = w>>2)
constexpr int ROWS = 16;

typedef unsigned int   uint;
typedef unsigned short ushort;
typedef unsigned long long ull;
typedef _Float16 half8 __attribute__((ext_vector_type(8)));
typedef float    f32x4 __attribute__((ext_vector_type(4)));

// ---- ws byte offsets ----
constexpr size_t OFF_W16 = 0;                                    // ushort [1024][1024] fp16 W = 2 MB
constexpr size_t OFF_INP = 2ull * 1024 * 1024;                   // float [T][NH][BATCH] = 32 MB
constexpr size_t OFF_SCT = OFF_INP + (size_t)T * NH * BATCH * 4; // ushort [2][64][1024] = 256 KB
constexpr size_t OFF_STF = OFF_SCT + 2ull * 64 * 1024 * 2;       // float [BATCH][NH] = 128 KB
constexpr size_t OFF_FLG = OFF_STF + (size_t)BATCH * NH * 4;     // flags, 8 KB

__device__ __forceinline__ ull ld64(const ull* p) {
  return __hip_atomic_load(p, __ATOMIC_RELAXED, __HIP_MEMORY_SCOPE_AGENT);
}
__device__ __forceinline__ void st32(uint* p, uint v) {
  __hip_atomic_store(p, v, __ATOMIC_RELAXED, __HIP_MEMORY_SCOPE_AGENT);
}

// Parallel-flag grid barrier (proven in R4): one release store + 64 independent polls.
__device__ __forceinline__ void gbar(unsigned* flags, unsigned step, int tid, int bid) {
  __syncthreads();
  if (tid == 0)
    __hip_atomic_store(&flags[bid * 32], step, __ATOMIC_RELEASE, __HIP_MEMORY_SCOPE_AGENT);
  if (tid < NBLK)
    while (__hip_atomic_load(&flags[tid * 32], __ATOMIC_RELAXED, __HIP_MEMORY_SCOPE_AGENT) < step)
      __builtin_amdgcn_s_sleep(1);
  __syncthreads();
}

// ---- prep: W -> fp16 ----
__global__ __launch_bounds__(256) void prep_w16(const float* __restrict__ Wh,
                                                ushort* __restrict__ w16) {
  const int m = blockIdx.x * 256 + threadIdx.x;
  w16[m] = __builtin_bit_cast(ushort, (_Float16)Wh[m]);
}

// ---- prep: inp[t][i][b] = Wi_w[i,:]·x[t,b,:] + Wi_b[i] + omega[i] ----
__global__ __launch_bounds__(256) void prep_inp(const float* __restrict__ x,
                                                const float* __restrict__ Wi_w,
                                                const float* __restrict__ Wi_b,
                                                const float* __restrict__ omega,
                                                float* __restrict__ inp) {
  const int t  = blockIdx.x;
  const int il = threadIdx.x >> 5, b = threadIdx.x & 31;
  const int i  = blockIdx.y * 8 + il;
  const float* xr = x + ((size_t)t * BATCH + b) * NIN;
  const float* wr = Wi_w + (size_t)i * NIN;
  float acc = Wi_b[i] + omega[i];
#pragma unroll
  for (int k = 0; k < NIN; ++k) acc += xr[k] * wr[k];
  inp[((size_t)t * NH + i) * BATCH + b] = acc;
}

// ---- the scan: W in registers, MFMA matvec, state via LLC ----
__global__ __launch_bounds__(NTHR, 2) void kuramoto_scan(
    const float*  __restrict__ inp,   // [T][NH][BATCH]
    const ushort* __restrict__ w16,   // [1024][1024] fp16
    ushort*       __restrict__ scT,   // [2][64][1024]: rows 0-31 sin[b], 32-63 cos[b]
    float*        __restrict__ stF,   // [BATCH][NH]
    unsigned*     __restrict__ flags)
{
  // D-partials: pd[khalf][ntile][col(n)][row(i)], row-stride 20 (16B-aligned, 2-way banks)
  __shared__ float pd[2 * 4 * 16 * 20];   // 10 KB

  const int tid  = threadIdx.x;
  const int bid  = blockIdx.x;
  const int lane = tid & 63;
  const int w    = tid >> 6;
  const int nt   = w & 3;          // N-tile: 0,1 = sin b0-15/b16-31 ; 2,3 = cos
  const int kh   = w >> 2;         // K-half
  const int m    = lane & 15;      // A: row index / B: col index / D: col index
  const int quad = lane >> 4;
  const int i0   = bid * ROWS;

  // ---- A-fragments (W rows) once into registers: 16 frags x 4 VGPR = 64 VGPRs ----
  half8 af[16];
  {
    const ushort* wbase = w16 + (size_t)(i0 + m) * NH + kh * 512 + quad * 8;
#pragma unroll
    for (int ks = 0; ks < 16; ++ks)
      af[ks] = __builtin_bit_cast(half8, *(const uint4*)(wbase + ks * 32));
  }

  // ---- theta-phase identity: thread = (il = tid&15, b = tid>>4) ----
  const int il  = tid & 15;
  const int b   = tid >> 4;
  const int i   = i0 + il;
  float th = 0.f, s_own = 0.f, c_own = 1.f;

  // ---- init parity-0 state: paired-lane packed uint stores ----
  {
    ushort* dst = scT;   // parity 0
    if ((il & 1) == 0) st32((uint*)(dst + (size_t)b * NH + i), 0x00000000u);        // sin = 0,0
    else               st32((uint*)(dst + (size_t)(32 + b) * NH + (i - 1)), 0x3C003C00u); // cos = 1,1
  }

  unsigned step = 1;
  gbar(flags, step, tid, bid); ++step;

  const int n = nt * 16 + m;       // my B/D column (state row in scT)

  for (int t = 0; t < T; ++t) {
    const int p = t & 1;
    const ushort* srcT = scT + (size_t)p * 64 * NH;

    // ---- B-fragments from LLC (relaxed agent 64-bit loads, L2-bypassing) ----
    const ull* bb = (const ull*)(srcT + (size_t)n * NH + kh * 512) + quad * 2;
    uint4 bf[16];
#pragma unroll
    for (int ks = 0; ks < 16; ++ks) {
      const ull lo = ld64(bb + ks * 8);
      const ull hi = ld64(bb + ks * 8 + 1);
      bf[ks] = make_uint4((uint)lo, (uint)(lo >> 32), (uint)hi, (uint)(hi >> 32));
    }

    // ---- MFMA: D[i(0..15)][n] += A(16x512) · B(512x16) ----
    f32x4 D = {0.f, 0.f, 0.f, 0.f};
#pragma unroll
    for (int ks = 0; ks < 16; ++ks)
      D = __builtin_amdgcn_mfma_f32_16x16x32_f16(af[ks], __builtin_bit_cast(half8, bf[ks]), D, 0, 0, 0);

    // lane holds D rows quad*4..+3 of column m  ->  pd[kh][nt][m][quad*4..+3]
    *(f32x4*)&pd[(((kh * 4 + nt) * 16) + m) * 20 + quad * 4] = D;
    __syncthreads();

    // ---- theta update for (i, b) ----
    const int sTile = b >> 4, cb = b & 15;
    const float S = pd[((0 + sTile) * 16 + cb) * 20 + il] + pd[((4 + sTile) * 16 + cb) * 20 + il];
    const float C = pd[((2 + sTile) * 16 + cb) * 20 + il] + pd[((6 + sTile) * 16 + cb) * 20 + il];
    const float coup = s_own * C - c_own * S;   // sin*ΣWcos - cos*ΣWsin
    const float inpv = inp[((size_t)t * NH + i) * BATCH + b];
    th = fmodf(coup + inpv + th, TWO_PI_F);
    if (th < 0.f) th += TWO_PI_F;
    float s, c;
    sincosf(th, &s, &c);
    s_own = s; c_own = c;

    if (t == T - 1) break;

    // ---- publish fp16 state, paired lanes -> one uint store each ----
    const uint hs = __builtin_bit_cast(ushort, (_Float16)s);
    const uint hc = __builtin_bit_cast(ushort, (_Float16)c);
    const uint phs = (uint)__shfl_xor((int)hs, 1, 64);
    const uint phc = (uint)__shfl_xor((int)hc, 1, 64);
    ushort* dst = scT + (size_t)(p ^ 1) * 64 * NH;
    if ((il & 1) == 0) st32((uint*)(dst + (size_t)b * NH + i), hs | (phs << 16));
    else               st32((uint*)(dst + (size_t)(32 + b) * NH + (i - 1)), phc | (hc << 16));

    gbar(flags, step, tid, bid); ++step;
  }

  stF[(size_t)b * NH + i] = th;
}

// ---- readout ----
__global__ void readout(const float* __restrict__ stF,
                        const float* __restrict__ Wout,   // [10][1024]
                        const float* __restrict__ bout,   // [10]
                        float* __restrict__ out)          // [32][10]
{
  const int bb = blockIdx.x;
  const int lane = threadIdx.x;   // 64 threads
  float st[16];
#pragma unroll
  for (int u = 0; u < 16; ++u) st[u] = stF[(size_t)bb * NH + u * 64 + lane];
  for (int o = 0; o < NOUT; ++o) {
    float acc = 0.f;
#pragma unroll
    for (int u = 0; u < 16; ++u) acc += st[u] * Wout[o * NH + u * 64 + lane];
#pragma unroll
    for (int sh = 1; sh < 64; sh <<= 1) acc += __shfl_xor(acc, sh, 64);
    if (lane == 0) out[bb * NOUT + o] = acc + bout[o];
  }
}

extern "C" void kernel_launch(void* const* d_in, const int* in_sizes, int n_in,
                              void* d_out, int out_size, void* d_ws, size_t ws_size,
                              hipStream_t stream) {
  const float* x     = (const float*)d_in[0];
  const float* Wi_w  = (const float*)d_in[1];
  const float* Wi_b  = (const float*)d_in[2];
  const float* Wh    = (const float*)d_in[3];
  const float* omega = (const float*)d_in[4];
  const float* W_out = (const float*)d_in[5];
  const float* b_out = (const float*)d_in[6];

  char* ws = (char*)d_ws;
  ushort*   w16 = (ushort*)(ws + OFF_W16);
  float*    inp = (float*)(ws + OFF_INP);
  ushort*   scT = (ushort*)(ws + OFF_SCT);
  float*    stF = (float*)(ws + OFF_STF);
  unsigned* flg = (unsigned*)(ws + OFF_FLG);

  hipMemsetAsync(ws + OFF_FLG, 0, 8192, stream);

  prep_w16<<<dim3(NH * NH / 256), dim3(256), 0, stream>>>(Wh, w16);
  prep_inp<<<dim3(T, NH / 8), dim3(256), 0, stream>>>(x, Wi_w, Wi_b, omega, inp);

  void* args[] = { (void*)&inp, (void*)&w16, (void*)&scT, (void*)&stF, (void*)&flg };
  hipError_t err = hipLaunchCooperativeKernel((const void*)kuramoto_scan,
                                              dim3(NBLK), dim3(NTHR), args, 0, stream);
  if (err != hipSuccess) {
    // 64 blocks at <=2 blocks/CU are trivially co-resident; normal launch is safe.
    (void)hipGetLastError();
    kuramoto_scan<<<dim3(NBLK), dim3(NTHR), 0, stream>>>(inp, w16, scT, stF, flg);
  }

  readout<<<dim3(BATCH), dim3(64), 0, stream>>>(stF, W_out, b_out, (float*)d_out);
}

// Round 6
// 1711.887 us; speedup vs baseline: 11.5692x; 1.5119x over previous
//
#include <hip/hip_runtime.h>
#include <hip/hip_fp16.h>
#include <math.h>

#define TWO_PI_F 6.2831853071795864769f

constexpr int T     = 256;
constexpr int BATCH = 32;
constexpr int NIN   = 28;
constexpr int NH    = 1024;
constexpr int NOUT  = 10;

constexpr int NBLK = 64;          // block k owns hidden rows [16k, 16k+16)
constexpr int NTHR = 512;         // 8 waves: wave w -> (ntile = w&3, khalf = w>>2)
constexpr int ROWS = 16;

typedef unsigned int   uint;
typedef unsigned short ushort;
typedef unsigned long long ull;
typedef _Float16 half8 __attribute__((ext_vector_type(8)));
typedef float    f32x4 __attribute__((ext_vector_type(4)));

// ---- ws byte offsets ----
constexpr size_t OFF_W16 = 0;                                    // ushort [1024][1024] fp16 W = 2 MB
constexpr size_t OFF_INP = 2ull * 1024 * 1024;                   // float [T][NH][BATCH] = 32 MB
constexpr size_t OFF_SCT = OFF_INP + (size_t)T * NH * BATCH * 4; // ushort [2][64][1024] = 256 KB
constexpr size_t OFF_STF = OFF_SCT + 2ull * 64 * 1024 * 2;       // float [BATCH][NH] = 128 KB
constexpr size_t OFF_FLG = OFF_STF + (size_t)BATCH * NH * 4;     // flags, 8 KB

__device__ __forceinline__ void st32(uint* p, uint v) {
  __hip_atomic_store(p, v, __ATOMIC_RELAXED, __HIP_MEMORY_SCOPE_AGENT);
}

// Batched device-scope (sc1) B-fragment load: 16 x dwordx4 at 64B stride from
// one base, ONE waitcnt. Replaces 32 latency-serialized atomic loads (the R5
// 9.5us/step bound). sc1 = same cache-bypass bits the agent-scope atomic-load
// lowering emits, so coherence vs the sc1 publish stores is unchanged.
__device__ __forceinline__ void ldB(const ushort* base, uint4 bf[16]) {
  asm volatile(
    "global_load_dwordx4 %0, %16, off sc1\n\t"
    "global_load_dwordx4 %1, %16, off offset:64 sc1\n\t"
    "global_load_dwordx4 %2, %16, off offset:128 sc1\n\t"
    "global_load_dwordx4 %3, %16, off offset:192 sc1\n\t"
    "global_load_dwordx4 %4, %16, off offset:256 sc1\n\t"
    "global_load_dwordx4 %5, %16, off offset:320 sc1\n\t"
    "global_load_dwordx4 %6, %16, off offset:384 sc1\n\t"
    "global_load_dwordx4 %7, %16, off offset:448 sc1\n\t"
    "global_load_dwordx4 %8, %16, off offset:512 sc1\n\t"
    "global_load_dwordx4 %9, %16, off offset:576 sc1\n\t"
    "global_load_dwordx4 %10, %16, off offset:640 sc1\n\t"
    "global_load_dwordx4 %11, %16, off offset:704 sc1\n\t"
    "global_load_dwordx4 %12, %16, off offset:768 sc1\n\t"
    "global_load_dwordx4 %13, %16, off offset:832 sc1\n\t"
    "global_load_dwordx4 %14, %16, off offset:896 sc1\n\t"
    "global_load_dwordx4 %15, %16, off offset:960 sc1\n\t"
    "s_waitcnt vmcnt(0)"
    : "=&v"(bf[0]), "=&v"(bf[1]), "=&v"(bf[2]), "=&v"(bf[3]),
      "=&v"(bf[4]), "=&v"(bf[5]), "=&v"(bf[6]), "=&v"(bf[7]),
      "=&v"(bf[8]), "=&v"(bf[9]), "=&v"(bf[10]), "=&v"(bf[11]),
      "=&v"(bf[12]), "=&v"(bf[13]), "=&v"(bf[14]), "=&v"(bf[15])
    : "v"(base)
    : "memory");
}

// Parallel-flag grid barrier (proven R4/R5): one release store + 64 independent polls.
__device__ __forceinline__ void gbar(unsigned* flags, unsigned step, int tid, int bid) {
  __syncthreads();
  if (tid == 0)
    __hip_atomic_store(&flags[bid * 32], step, __ATOMIC_RELEASE, __HIP_MEMORY_SCOPE_AGENT);
  if (tid < NBLK)
    while (__hip_atomic_load(&flags[tid * 32], __ATOMIC_RELAXED, __HIP_MEMORY_SCOPE_AGENT) < step)
      __builtin_amdgcn_s_sleep(1);
  __syncthreads();
}

// ---- prep: W -> fp16 ----
__global__ __launch_bounds__(256) void prep_w16(const float* __restrict__ Wh,
                                                ushort* __restrict__ w16) {
  const int m = blockIdx.x * 256 + threadIdx.x;
  w16[m] = __builtin_bit_cast(ushort, (_Float16)Wh[m]);
}

// ---- prep: inp[t][i][b] = Wi_w[i,:]·x[t,b,:] + Wi_b[i] + omega[i] ----
__global__ __launch_bounds__(256) void prep_inp(const float* __restrict__ x,
                                                const float* __restrict__ Wi_w,
                                                const float* __restrict__ Wi_b,
                                                const float* __restrict__ omega,
                                                float* __restrict__ inp) {
  const int t  = blockIdx.x;
  const int il = threadIdx.x >> 5, b = threadIdx.x & 31;
  const int i  = blockIdx.y * 8 + il;
  const float* xr = x + ((size_t)t * BATCH + b) * NIN;
  const float* wr = Wi_w + (size_t)i * NIN;
  float acc = Wi_b[i] + omega[i];
#pragma unroll
  for (int k = 0; k < NIN; ++k) acc += xr[k] * wr[k];
  inp[((size_t)t * NH + i) * BATCH + b] = acc;
}

// ---- the scan: W in registers, MFMA matvec, state via LLC ----
__global__ __launch_bounds__(NTHR, 2) void kuramoto_scan(
    const float*  __restrict__ inp,   // [T][NH][BATCH]
    const ushort* __restrict__ w16,   // [1024][1024] fp16
    ushort*       __restrict__ scT,   // [2][64][1024]: rows 0-31 sin[b], 32-63 cos[b]
    float*        __restrict__ stF,   // [BATCH][NH]
    unsigned*     __restrict__ flags)
{
  // D-partials: pd[khalf][ntile][col(n)][row(i)], row-stride 20 (16B-aligned, 2-way banks)
  __shared__ float pd[2 * 4 * 16 * 20];   // 10 KB

  const int tid  = threadIdx.x;
  const int bid  = blockIdx.x;
  const int lane = tid & 63;
  const int w    = tid >> 6;
  const int nt   = w & 3;          // N-tile: 0,1 = sin b0-15/b16-31 ; 2,3 = cos
  const int kh   = w >> 2;         // K-half
  const int m    = lane & 15;      // A: row index / B: col index / D: col index
  const int quad = lane >> 4;
  const int i0   = bid * ROWS;

  // ---- A-fragments (W rows) once into registers: 16 frags x 4 VGPR = 64 regs ----
  half8 af[16];
  {
    const ushort* wbase = w16 + (size_t)(i0 + m) * NH + kh * 512 + quad * 8;
#pragma unroll
    for (int ks = 0; ks < 16; ++ks)
      af[ks] = __builtin_bit_cast(half8, *(const uint4*)(wbase + ks * 32));
  }

  // ---- theta-phase identity: thread = (il = tid&15, b = tid>>4) ----
  const int il  = tid & 15;
  const int b   = tid >> 4;
  const int i   = i0 + il;
  float th = 0.f, s_own = 0.f, c_own = 1.f;

  // ---- init parity-0 state: paired-lane packed uint stores ----
  {
    ushort* dst = scT;   // parity 0
    if ((il & 1) == 0) st32((uint*)(dst + (size_t)b * NH + i), 0x00000000u);        // sin = 0,0
    else               st32((uint*)(dst + (size_t)(32 + b) * NH + (i - 1)), 0x3C003C00u); // cos = 1,1
  }

  unsigned step = 1;
  gbar(flags, step, tid, bid); ++step;

  const int n = nt * 16 + m;       // my B/D column (state row in scT)

  for (int t = 0; t < T; ++t) {
    const int p = t & 1;
    const ushort* srcT = scT + (size_t)p * 64 * NH;

    // issue the inp load before the B-load batch so it rides the same window
    const float inpv = inp[((size_t)t * NH + i) * BATCH + b];

    // ---- B-fragments: one batched sc1 load burst, one waitcnt ----
    uint4 bf[16];
    ldB(srcT + (size_t)n * NH + kh * 512 + quad * 8, bf);

    // ---- MFMA: D[i(0..15)][n] += A(16x512) · B(512x16), same ks order as R5 ----
    f32x4 D = {0.f, 0.f, 0.f, 0.f};
#pragma unroll
    for (int ks = 0; ks < 16; ++ks)
      D = __builtin_amdgcn_mfma_f32_16x16x32_f16(af[ks], __builtin_bit_cast(half8, bf[ks]), D, 0, 0, 0);

    // lane holds D rows quad*4..+3 of column m  ->  pd[kh][nt][m][quad*4..+3]
    *(f32x4*)&pd[(((kh * 4 + nt) * 16) + m) * 20 + quad * 4] = D;
    __syncthreads();

    // ---- theta update for (i, b) ----
    const int sTile = b >> 4, cb = b & 15;
    const float S = pd[((0 + sTile) * 16 + cb) * 20 + il] + pd[((4 + sTile) * 16 + cb) * 20 + il];
    const float C = pd[((2 + sTile) * 16 + cb) * 20 + il] + pd[((6 + sTile) * 16 + cb) * 20 + il];
    const float coup = s_own * C - c_own * S;   // sin*ΣWcos - cos*ΣWsin
    th = fmodf(coup + inpv + th, TWO_PI_F);
    if (th < 0.f) th += TWO_PI_F;
    float s, c;
    sincosf(th, &s, &c);
    s_own = s; c_own = c;

    if (t == T - 1) break;

    // ---- publish fp16 state, paired lanes -> one uint store each ----
    const uint hs = __builtin_bit_cast(ushort, (_Float16)s);
    const uint hc = __builtin_bit_cast(ushort, (_Float16)c);
    const uint phs = (uint)__shfl_xor((int)hs, 1, 64);
    const uint phc = (uint)__shfl_xor((int)hc, 1, 64);
    ushort* dst = scT + (size_t)(p ^ 1) * 64 * NH;
    if ((il & 1) == 0) st32((uint*)(dst + (size_t)b * NH + i), hs | (phs << 16));
    else               st32((uint*)(dst + (size_t)(32 + b) * NH + (i - 1)), phc | (hc << 16));

    gbar(flags, step, tid, bid); ++step;
  }

  stF[(size_t)b * NH + i] = th;
}

// ---- readout ----
__global__ void readout(const float* __restrict__ stF,
                        const float* __restrict__ Wout,   // [10][1024]
                        const float* __restrict__ bout,   // [10]
                        float* __restrict__ out)          // [32][10]
{
  const int bb = blockIdx.x;
  const int lane = threadIdx.x;   // 64 threads
  float st[16];
#pragma unroll
  for (int u = 0; u < 16; ++u) st[u] = stF[(size_t)bb * NH + u * 64 + lane];
  for (int o = 0; o < NOUT; ++o) {
    float acc = 0.f;
#pragma unroll
    for (int u = 0; u < 16; ++u) acc += st[u] * Wout[o * NH + u * 64 + lane];
#pragma unroll
    for (int sh = 1; sh < 64; sh <<= 1) acc += __shfl_xor(acc, sh, 64);
    if (lane == 0) out[bb * NOUT + o] = acc + bout[o];
  }
}

extern "C" void kernel_launch(void* const* d_in, const int* in_sizes, int n_in,
                              void* d_out, int out_size, void* d_ws, size_t ws_size,
                              hipStream_t stream) {
  const float* x     = (const float*)d_in[0];
  const float* Wi_w  = (const float*)d_in[1];
  const float* Wi_b  = (const float*)d_in[2];
  const float* Wh    = (const float*)d_in[3];
  const float* omega = (const float*)d_in[4];
  const float* W_out = (const float*)d_in[5];
  const float* b_out = (const float*)d_in[6];

  char* ws = (char*)d_ws;
  ushort*   w16 = (ushort*)(ws + OFF_W16);
  float*    inp = (float*)(ws + OFF_INP);
  ushort*   scT = (ushort*)(ws + OFF_SCT);
  float*    stF = (float*)(ws + OFF_STF);
  unsigned* flg = (unsigned*)(ws + OFF_FLG);

  hipMemsetAsync(ws + OFF_FLG, 0, 8192, stream);

  prep_w16<<<dim3(NH * NH / 256), dim3(256), 0, stream>>>(Wh, w16);
  prep_inp<<<dim3(T, NH / 8), dim3(256), 0, stream>>>(x, Wi_w, Wi_b, omega, inp);

  void* args[] = { (void*)&inp, (void*)&w16, (void*)&scT, (void*)&stF, (void*)&flg };
  hipError_t err = hipLaunchCooperativeKernel((const void*)kuramoto_scan,
                                              dim3(NBLK), dim3(NTHR), args, 0, stream);
  if (err != hipSuccess) {
    // 64 blocks at <=2 blocks/CU are trivially co-resident; normal launch is safe.
    (void)hipGetLastError();
    kuramoto_scan<<<dim3(NBLK), dim3(NTHR), 0, stream>>>(inp, w16, scT, stF, flg);
  }

  readout<<<dim3(BATCH), dim3(64), 0, stream>>>(stF, W_out, b_out, (float*)d_out);
}

// Round 8
// 1675.780 us; speedup vs baseline: 11.8184x; 1.0215x over previous
//
#include <hip/hip_runtime.h>
#include <hip/hip_fp16.h>
#include <math.h>

#define TWO_PI_F 6.2831853071795864769f

constexpr int T     = 256;
constexpr int BATCH = 32;
constexpr int NIN   = 28;
constexpr int NH    = 1024;
constexpr int NOUT  = 10;

constexpr int NBLK = 64;     // 16 row-groups x 4 batch-groups
constexpr int NTHR = 512;    // 8 waves: wave w -> (row-tile = w&3, khalf = w>>2)
constexpr int BROWS = 64;    // rows per block
constexpr int BB    = 8;     // batches per block

typedef unsigned int   uint;
typedef unsigned short ushort;
typedef unsigned long long ull;
typedef _Float16 half8 __attribute__((ext_vector_type(8)));
typedef float    f32x4 __attribute__((ext_vector_type(4)));

// ---- ws byte offsets ----
constexpr size_t OFF_W16 = 0;                                    // ushort [1024][1024] fp16 W = 2 MB
constexpr size_t OFF_INP = 2ull * 1024 * 1024;                   // float [T][BATCH][NH] = 32 MB
constexpr size_t OFF_SCT = OFF_INP + (size_t)T * NH * BATCH * 4; // ushort [2][4][16][1024] = 256 KB
constexpr size_t OFF_STF = OFF_SCT + 2ull * 4 * 16 * 1024 * 2;   // float [BATCH][NH] = 128 KB
constexpr size_t OFF_FLG = OFF_STF + (size_t)BATCH * NH * 4;     // flags, 8 KB

__device__ __forceinline__ void st32(uint* p, uint v) {
  __hip_atomic_store(p, v, __ATOMIC_RELAXED, __HIP_MEMORY_SCOPE_AGENT);
}

// Batched device-scope (sc1) B-fragment load: 16 x dwordx4 at 64B stride from
// one base, ONE waitcnt (R6-proven).
__device__ __forceinline__ void ldB(const ushort* base, uint4 bf[16]) {
  asm volatile(
    "global_load_dwordx4 %0, %16, off sc1\n\t"
    "global_load_dwordx4 %1, %16, off offset:64 sc1\n\t"
    "global_load_dwordx4 %2, %16, off offset:128 sc1\n\t"
    "global_load_dwordx4 %3, %16, off offset:192 sc1\n\t"
    "global_load_dwordx4 %4, %16, off offset:256 sc1\n\t"
    "global_load_dwordx4 %5, %16, off offset:320 sc1\n\t"
    "global_load_dwordx4 %6, %16, off offset:384 sc1\n\t"
    "global_load_dwordx4 %7, %16, off offset:448 sc1\n\t"
    "global_load_dwordx4 %8, %16, off offset:512 sc1\n\t"
    "global_load_dwordx4 %9, %16, off offset:576 sc1\n\t"
    "global_load_dwordx4 %10, %16, off offset:640 sc1\n\t"
    "global_load_dwordx4 %11, %16, off offset:704 sc1\n\t"
    "global_load_dwordx4 %12, %16, off offset:768 sc1\n\t"
    "global_load_dwordx4 %13, %16, off offset:832 sc1\n\t"
    "global_load_dwordx4 %14, %16, off offset:896 sc1\n\t"
    "global_load_dwordx4 %15, %16, off offset:960 sc1\n\t"
    "s_waitcnt vmcnt(0)"
    : "=&v"(bf[0]), "=&v"(bf[1]), "=&v"(bf[2]), "=&v"(bf[3]),
      "=&v"(bf[4]), "=&v"(bf[5]), "=&v"(bf[6]), "=&v"(bf[7]),
      "=&v"(bf[8]), "=&v"(bf[9]), "=&v"(bf[10]), "=&v"(bf[11]),
      "=&v"(bf[12]), "=&v"(bf[13]), "=&v"(bf[14]), "=&v"(bf[15])
    : "v"(base)
    : "memory");
}

// Grid barrier, R6-proven form. RELEASE on the flag store is REQUIRED:
// R7 showed sc1-store + __syncthreads vmcnt-drain + relaxed flag is not a
// publish (drain = ACK, not global visibility); the release's cache
// maintenance provides the ordering.
__device__ __forceinline__ void gbar(unsigned* flags, unsigned step, int tid, int bid) {
  __syncthreads();
  if (tid == 0)
    __hip_atomic_store(&flags[bid * 32], step, __ATOMIC_RELEASE, __HIP_MEMORY_SCOPE_AGENT);
  if (tid < NBLK)
    while (__hip_atomic_load(&flags[tid * 32], __ATOMIC_RELAXED, __HIP_MEMORY_SCOPE_AGENT) < step)
      __builtin_amdgcn_s_sleep(1);
  __syncthreads();
}

// ---- prep: W -> fp16 ----
__global__ __launch_bounds__(256) void prep_w16(const float* __restrict__ Wh,
                                                ushort* __restrict__ w16) {
  const int m = blockIdx.x * 256 + threadIdx.x;
  w16[m] = __builtin_bit_cast(ushort, (_Float16)Wh[m]);
}

// ---- prep: inp[t][b][i] = Wi_w[i,:]·x[t,b,:] + Wi_b[i] + omega[i] ----
__global__ __launch_bounds__(256) void prep_inp(const float* __restrict__ x,
                                                const float* __restrict__ Wi_w,
                                                const float* __restrict__ Wi_b,
                                                const float* __restrict__ omega,
                                                float* __restrict__ inp) {
  const int t = blockIdx.x;
  const int b = blockIdx.y;
  const float* xr = x + ((size_t)t * BATCH + b) * NIN;
#pragma unroll
  for (int u = 0; u < 4; ++u) {
    const int i = u * 256 + threadIdx.x;
    const float* wr = Wi_w + (size_t)i * NIN;
    float acc = Wi_b[i] + omega[i];
#pragma unroll
    for (int k = 0; k < NIN; ++k) acc += xr[k] * wr[k];
    inp[((size_t)t * BATCH + b) * NH + i] = acc;
  }
}

// ---- the scan: block = (row-group, batch-group); 2 MB/step LLC exchange ----
__global__ __launch_bounds__(NTHR, 2) void kuramoto_scan(
    const float*  __restrict__ inp,   // [T][BATCH][NH]
    const ushort* __restrict__ w16,   // [1024][1024] fp16
    ushort*       __restrict__ scT,   // [2][4 bg][16 n][1024 i]; n: 0-7 sin, 8-15 cos
    float*        __restrict__ stF,   // [BATCH][NH]
    unsigned*     __restrict__ flags)
{
  // D-partials: pd[kh][rt][n][row16 (+4 pad)]
  __shared__ float pd[2 * 4 * 16 * 20];   // 10 KB

  const int tid  = threadIdx.x;
  const int bid  = blockIdx.x;
  const int rg   = bid >> 2;       // row-group: rows rg*64 .. +63
  const int bg   = bid & 3;        // batch-group: batches bg*8 .. +7
  const int lane = tid & 63;
  const int w    = tid >> 6;
  const int rt   = w & 3;          // row-tile within block (16 rows)
  const int kh   = w >> 2;         // K-half
  const int m    = lane & 15;      // A: M index / B,D: N index
  const int quad = lane >> 4;

  // ---- A-fragments (W rows) once into registers: 16 frags x 4 VGPR ----
  half8 af[16];
  {
    const ushort* wbase = w16 + (size_t)(rg * 64 + rt * 16 + m) * NH + kh * 512 + quad * 8;
#pragma unroll
    for (int ks = 0; ks < 16; ++ks)
      af[ks] = __builtin_bit_cast(half8, *(const uint4*)(wbase + ks * 32));
  }

  // ---- theta-phase identity: thread = (b_local = tid>>6, i_local = tid&63) ----
  const int bl = tid >> 6;         // 0..7
  const int ilc = tid & 63;        // 0..63
  const int i  = rg * 64 + ilc;    // my hidden unit
  const int b  = bg * 8 + bl;      // my batch
  float th = 0.f, s_own = 0.f, c_own = 1.f;

  // ---- init parity-0 state: paired-lane packed uint stores ----
  {
    if ((ilc & 1) == 0)
      st32((uint*)(scT + ((size_t)(0 * 4 + bg) * 16 + bl) * 1024 + i), 0x00000000u);       // sin = 0,0
    else
      st32((uint*)(scT + ((size_t)(0 * 4 + bg) * 16 + bl + 8) * 1024 + (i - 1)), 0x3C003C00u); // cos = 1,1
  }

  unsigned step = 1;
  gbar(flags, step, tid, bid); ++step;

  for (int t = 0; t < T; ++t) {
    const int p = t & 1;

    // issue the inp load before the B-load burst so it rides the same window
    const float inpv = inp[((size_t)t * BATCH + b) * NH + i];

    // ---- B-fragments: my batch-group's 16 state rows only (32 KB/block) ----
    uint4 bf[16];
    ldB(scT + ((size_t)(p * 4 + bg) * 16 + m) * 1024 + kh * 512 + quad * 8, bf);

    // ---- MFMA: two independent 8-chains, then add ----
    f32x4 D0 = {0.f, 0.f, 0.f, 0.f}, D1 = {0.f, 0.f, 0.f, 0.f};
#pragma unroll
    for (int ks = 0; ks < 8; ++ks)
      D0 = __builtin_amdgcn_mfma_f32_16x16x32_f16(af[ks], __builtin_bit_cast(half8, bf[ks]), D0, 0, 0, 0);
#pragma unroll
    for (int ks = 8; ks < 16; ++ks)
      D1 = __builtin_amdgcn_mfma_f32_16x16x32_f16(af[ks], __builtin_bit_cast(half8, bf[ks]), D1, 0, 0, 0);
    const f32x4 D = D0 + D1;

    // lane holds D rows quad*4..+3 (M) of column m (N) -> pd[kh][rt][m][quad*4..]
    *(f32x4*)&pd[(((kh * 4 + rt) * 16) + m) * 20 + quad * 4] = D;
    __syncthreads();

    // ---- theta update for (i, b) ----
    const int rti = ilc >> 4, r16 = ilc & 15;
    const float S = pd[((0 + rti) * 16 + bl) * 20 + r16] + pd[((4 + rti) * 16 + bl) * 20 + r16];
    const float C = pd[((0 + rti) * 16 + bl + 8) * 20 + r16] + pd[((4 + rti) * 16 + bl + 8) * 20 + r16];
    const float coup = s_own * C - c_own * S;   // sin*ΣWcos - cos*ΣWsin
    th = fmodf(coup + inpv + th, TWO_PI_F);
    if (th < 0.f) th += TWO_PI_F;
    float s, c;
    sincosf(th, &s, &c);
    s_own = s; c_own = c;

    if (t == T - 1) break;

    // ---- publish fp16 state, paired lanes -> one uint store each ----
    const uint hs = __builtin_bit_cast(ushort, (_Float16)s);
    const uint hc = __builtin_bit_cast(ushort, (_Float16)c);
    const uint phs = (uint)__shfl_xor((int)hs, 1, 64);
    const uint phc = (uint)__shfl_xor((int)hc, 1, 64);
    const size_t dbase = (size_t)((p ^ 1) * 4 + bg) * 16;
    if ((ilc & 1) == 0)
      st32((uint*)(scT + (dbase + bl) * 1024 + i), hs | (phs << 16));
    else
      st32((uint*)(scT + (dbase + bl + 8) * 1024 + (i - 1)), phc | (hc << 16));

    gbar(flags, step, tid, bid); ++step;
  }

  stF[(size_t)b * NH + i] = th;
}

// ---- readout ----
__global__ void readout(const float* __restrict__ stF,
                        const float* __restrict__ Wout,   // [10][1024]
                        const float* __restrict__ bout,   // [10]
                        float* __restrict__ out)          // [32][10]
{
  const int bb = blockIdx.x;
  const int lane = threadIdx.x;   // 64 threads
  float st[16];
#pragma unroll
  for (int u = 0; u < 16; ++u) st[u] = stF[(size_t)bb * NH + u * 64 + lane];
  for (int o = 0; o < NOUT; ++o) {
    float acc = 0.f;
#pragma unroll
    for (int u = 0; u < 16; ++u) acc += st[u] * Wout[o * NH + u * 64 + lane];
#pragma unroll
    for (int sh = 1; sh < 64; sh <<= 1) acc += __shfl_xor(acc, sh, 64);
    if (lane == 0) out[bb * NOUT + o] = acc + bout[o];
  }
}

extern "C" void kernel_launch(void* const* d_in, const int* in_sizes, int n_in,
                              void* d_out, int out_size, void* d_ws, size_t ws_size,
                              hipStream_t stream) {
  const float* x     = (const float*)d_in[0];
  const float* Wi_w  = (const float*)d_in[1];
  const float* Wi_b  = (const float*)d_in[2];
  const float* Wh    = (const float*)d_in[3];
  const float* omega = (const float*)d_in[4];
  const float* W_out = (const float*)d_in[5];
  const float* b_out = (const float*)d_in[6];

  char* ws = (char*)d_ws;
  ushort*   w16 = (ushort*)(ws + OFF_W16);
  float*    inp = (float*)(ws + OFF_INP);
  ushort*   scT = (ushort*)(ws + OFF_SCT);
  float*    stF = (float*)(ws + OFF_STF);
  unsigned* flg = (unsigned*)(ws + OFF_FLG);

  hipMemsetAsync(ws + OFF_FLG, 0, 8192, stream);

  prep_w16<<<dim3(NH * NH / 256), dim3(256), 0, stream>>>(Wh, w16);
  prep_inp<<<dim3(T, BATCH), dim3(256), 0, stream>>>(x, Wi_w, Wi_b, omega, inp);

  void* args[] = { (void*)&inp, (void*)&w16, (void*)&scT, (void*)&stF, (void*)&flg };
  hipError_t err = hipLaunchCooperativeKernel((const void*)kuramoto_scan,
                                              dim3(NBLK), dim3(NTHR), args, 0, stream);
  if (err != hipSuccess) {
    // 64 blocks at <=2 blocks/CU are trivially co-resident; normal launch is safe.
    (void)hipGetLastError();
    kuramoto_scan<<<dim3(NBLK), dim3(NTHR), 0, stream>>>(inp, w16, scT, stF, flg);
  }

  readout<<<dim3(BATCH), dim3(64), 0, stream>>>(stF, W_out, b_out, (float*)d_out);
}